// Round 1
// baseline (1578.265 us; speedup 1.0000x reference)
//
#include <hip/hip_runtime.h>
#include <math.h>

// ---------------------------------------------------------------------------
// SourceGCNConvEncoder on MI355X.
// Pipeline: x1 = x@W1 ; x2 = mish(mish(conv1(x1))) ; x3 = [x1|x2]@W2 ;
//           x4 = mish(mish(conv2_rev(x3))) ; out = mish(x1+x2+x4)
// conv aggregation via device-built CSR (degree -> scan -> fill), gather-based.
// ---------------------------------------------------------------------------

#define NN 100000

__device__ __forceinline__ float mishf(float x) {
    // softplus stable: max(x,0) + log1p(exp(-|x|))  (== logaddexp(x,0))
    float sp = fmaxf(x, 0.0f) + log1pf(expf(-fabsf(x)));
    return x * tanhf(sp);
}
__device__ __forceinline__ float mish2f(float x) { return mishf(mishf(x)); }

// ---- degrees ---------------------------------------------------------------
__global__ void deg_kernel(const int* __restrict__ ei, int E,
                           int* __restrict__ deg_in, int* __restrict__ deg_out) {
    int e = blockIdx.x * blockDim.x + threadIdx.x;
    if (e < E) {
        atomicAdd(&deg_out[ei[e]], 1);     // row
        atomicAdd(&deg_in[ei[E + e]], 1);  // col
    }
}

// ---- 3-pass dual exclusive scan over N elems -------------------------------
__global__ void block_sums2(const int* __restrict__ a, const int* __restrict__ b,
                            int n, int* __restrict__ bsa, int* __restrict__ bsb) {
    __shared__ int sa[256], sb[256];
    int t = threadIdx.x;
    int i = blockIdx.x * 256 + t;
    sa[t] = (i < n) ? a[i] : 0;
    sb[t] = (i < n) ? b[i] : 0;
    __syncthreads();
    for (int s = 128; s > 0; s >>= 1) {
        if (t < s) { sa[t] += sa[t + s]; sb[t] += sb[t + s]; }
        __syncthreads();
    }
    if (t == 0) { bsa[blockIdx.x] = sa[0]; bsb[blockIdx.x] = sb[0]; }
}

__global__ void scan_small2(int* __restrict__ bsa, int* __restrict__ bsb, int nb) {
    __shared__ int sa[512], sb[512];
    int t = threadIdx.x;
    int va = (t < nb) ? bsa[t] : 0;
    int vb = (t < nb) ? bsb[t] : 0;
    sa[t] = va; sb[t] = vb;
    __syncthreads();
    for (int off = 1; off < 512; off <<= 1) {
        int xa = (t >= off) ? sa[t - off] : 0;
        int xb = (t >= off) ? sb[t - off] : 0;
        __syncthreads();
        sa[t] += xa; sb[t] += xb;
        __syncthreads();
    }
    if (t < nb) { bsa[t] = sa[t] - va; bsb[t] = sb[t] - vb; }  // exclusive
}

__global__ void scan_final2(const int* __restrict__ a, const int* __restrict__ b,
                            const int* __restrict__ bsa, const int* __restrict__ bsb,
                            int n, int* __restrict__ offa, int* __restrict__ offb) {
    __shared__ int sa[256], sb[256];
    int t = threadIdx.x;
    int i = blockIdx.x * 256 + t;
    int va = (i < n) ? a[i] : 0;
    int vb = (i < n) ? b[i] : 0;
    sa[t] = va; sb[t] = vb;
    __syncthreads();
    for (int off = 1; off < 256; off <<= 1) {
        int xa = (t >= off) ? sa[t - off] : 0;
        int xb = (t >= off) ? sb[t - off] : 0;
        __syncthreads();
        sa[t] += xa; sb[t] += xb;
        __syncthreads();
    }
    if (i < n) {
        offa[i] = bsa[blockIdx.x] + sa[t] - va;
        offb[i] = bsb[blockIdx.x] + sb[t] - vb;
        if (i == n - 1) {
            offa[n] = bsa[blockIdx.x] + sa[t];
            offb[n] = bsb[blockIdx.x] + sb[t];
        }
    }
}

// ---- CSR fill with per-edge norms ------------------------------------------
__global__ void fill_kernel(const int* __restrict__ ei, int E,
                            const int* __restrict__ deg_in, const int* __restrict__ deg_out,
                            const int* __restrict__ off1, const int* __restrict__ off2,
                            int* __restrict__ cur1, int* __restrict__ cur2,
                            int* __restrict__ src1, float* __restrict__ w1s,
                            int* __restrict__ src2, float* __restrict__ w2s,
                            const float* __restrict__ c1p, const float* __restrict__ c2p) {
    int e = blockIdx.x * blockDim.x + threadIdx.x;
    if (e >= E) return;
    int r = ei[e], c = ei[E + e];
    float din  = (float)deg_in[c];   // >=1 for existing edge
    float dout = (float)deg_out[r];  // >=1
    float invs = 1.0f / (din + dout);
    float n1 = c1p[0] * invs + 1.0f / din;   // conv1: aggregate at col, msg from row
    float n2 = c2p[0] * invs + 1.0f / dout;  // conv2(rev): aggregate at row, msg from col
    int p1 = off1[c] + atomicAdd(&cur1[c], 1);
    src1[p1] = r; w1s[p1] = n1;
    int p2 = off2[r] + atomicAdd(&cur2[r], 1);
    src2[p2] = c; w2s[p2] = n2;
}

// ---- fp32 GEMM: C[M,256] = A[M,K] * B[K,256]; 128x64 tile, 8x4/thread ------
#define BM 128
#define BN 64
#define BK 32
__launch_bounds__(256)
__global__ void sgemm128(const float* __restrict__ A, int lda,
                         const float* __restrict__ B, int ldb,
                         float* __restrict__ C, int ldc,
                         int M, int K) {
    __shared__ float As[BK][BM + 4];  // +4 pad keeps 16B alignment, breaks conflicts
    __shared__ float Bs[BK][BN];
    const int tid = threadIdx.x;
    const int bm = blockIdx.x * BM;
    const int bn = blockIdx.y * BN;
    const int tx = tid & 15;    // col group: cols tx*4 .. +3
    const int ty = tid >> 4;    // row group: rows ty*8 .. +7
    const int ar  = tid >> 3;   // A-load row 0..31 (+32*rr)
    const int ac4 = tid & 7;    // A-load float4 col
    const int br  = tid >> 4;   // B-load row 0..15 (+16*rr)
    const int bc4 = tid & 15;   // B-load float4 col

    float acc[8][4];
#pragma unroll
    for (int i = 0; i < 8; i++)
#pragma unroll
        for (int j = 0; j < 4; j++) acc[i][j] = 0.f;

    for (int k0 = 0; k0 < K; k0 += BK) {
#pragma unroll
        for (int rr = 0; rr < 4; ++rr) {
            int row = bm + ar + rr * 32;
            row = row < M ? row : M - 1;  // clamp; stores are guarded
            const float4 v = *(const float4*)(A + (size_t)row * lda + k0 + ac4 * 4);
            As[ac4 * 4 + 0][ar + rr * 32] = v.x;
            As[ac4 * 4 + 1][ar + rr * 32] = v.y;
            As[ac4 * 4 + 2][ar + rr * 32] = v.z;
            As[ac4 * 4 + 3][ar + rr * 32] = v.w;
        }
#pragma unroll
        for (int rr = 0; rr < 2; ++rr) {
            int row = k0 + br + rr * 16;
            *(float4*)&Bs[br + rr * 16][bc4 * 4] =
                *(const float4*)(B + (size_t)row * ldb + bn + bc4 * 4);
        }
        __syncthreads();
#pragma unroll
        for (int k = 0; k < BK; ++k) {
            float4 a4l = *(const float4*)&As[k][ty * 8];
            float4 a4h = *(const float4*)&As[k][ty * 8 + 4];
            float4 b4  = *(const float4*)&Bs[k][tx * 4];
            float a0[8] = {a4l.x, a4l.y, a4l.z, a4l.w, a4h.x, a4h.y, a4h.z, a4h.w};
            float b0[4] = {b4.x, b4.y, b4.z, b4.w};
#pragma unroll
            for (int i = 0; i < 8; i++)
#pragma unroll
                for (int j = 0; j < 4; j++)
                    acc[i][j] = fmaf(a0[i], b0[j], acc[i][j]);
        }
        __syncthreads();
    }
#pragma unroll
    for (int i = 0; i < 8; i++) {
        int row = bm + ty * 8 + i;
        if (row < M) {
            float4 v = make_float4(acc[i][0], acc[i][1], acc[i][2], acc[i][3]);
            *(float4*)(C + (size_t)row * ldc + bn + tx * 4) = v;
        }
    }
}

// ---- conv1 aggregation: x2 = mish(mish(sum norm1 * x1[src])) ---------------
// x1 lives in xcat cols [0,256); x2 written to xcat cols [256,512)
__global__ void aggregate1(const float* __restrict__ xcat,
                           const int* __restrict__ off, const int* __restrict__ src,
                           const float* __restrict__ wgt,
                           float* __restrict__ xcat_out, int n) {
    int node = blockIdx.x * 4 + (threadIdx.x >> 6);
    int lane = threadIdx.x & 63;
    if (node >= n) return;
    int s0 = off[node], s1 = off[node + 1];
    float ax = 0.f, ay = 0.f, az = 0.f, aw = 0.f;
    for (int j = s0; j < s1; ++j) {
        int s = src[j];
        float w = wgt[j];
        const float4 v = *(const float4*)(xcat + (size_t)s * 512 + lane * 4);
        ax = fmaf(w, v.x, ax); ay = fmaf(w, v.y, ay);
        az = fmaf(w, v.z, az); aw = fmaf(w, v.w, aw);
    }
    float4 o = make_float4(mish2f(ax), mish2f(ay), mish2f(az), mish2f(aw));
    *(float4*)(xcat_out + (size_t)node * 512 + 256 + lane * 4) = o;
}

// ---- conv2 aggregation + final fuse: out = mish(x1+x2+mish(mish(agg))) -----
__global__ void aggregate2(const float* __restrict__ x3,
                           const int* __restrict__ off, const int* __restrict__ src,
                           const float* __restrict__ wgt,
                           const float* __restrict__ xcat,
                           float* __restrict__ out, int n) {
    int node = blockIdx.x * 4 + (threadIdx.x >> 6);
    int lane = threadIdx.x & 63;
    if (node >= n) return;
    int s0 = off[node], s1 = off[node + 1];
    float ax = 0.f, ay = 0.f, az = 0.f, aw = 0.f;
    for (int j = s0; j < s1; ++j) {
        int s = src[j];
        float w = wgt[j];
        const float4 v = *(const float4*)(x3 + (size_t)s * 256 + lane * 4);
        ax = fmaf(w, v.x, ax); ay = fmaf(w, v.y, ay);
        az = fmaf(w, v.z, az); aw = fmaf(w, v.w, aw);
    }
    const float4 x1v = *(const float4*)(xcat + (size_t)node * 512 + lane * 4);
    const float4 x2v = *(const float4*)(xcat + (size_t)node * 512 + 256 + lane * 4);
    float4 o;
    o.x = mishf(x1v.x + x2v.x + mish2f(ax));
    o.y = mishf(x1v.y + x2v.y + mish2f(ay));
    o.z = mishf(x1v.z + x2v.z + mish2f(az));
    o.w = mishf(x1v.w + x2v.w + mish2f(aw));
    *(float4*)(out + (size_t)node * 256 + lane * 4) = o;
}

// ---------------------------------------------------------------------------
extern "C" void kernel_launch(void* const* d_in, const int* in_sizes, int n_in,
                              void* d_out, int out_size, void* d_ws, size_t ws_size,
                              hipStream_t stream) {
    const float* x  = (const float*)d_in[0];
    const int*   ei = (const int*)d_in[1];
    const float* W1 = (const float*)d_in[2];
    const float* W2 = (const float*)d_in[3];
    const float* c1 = (const float*)d_in[4];
    const float* c2 = (const float*)d_in[5];
    float* out = (float*)d_out;

    const int N = in_sizes[0] / 512;  // 100000
    const int E = in_sizes[1] / 2;    // 800000

    // workspace carve-up (256B aligned)
    char* p = (char*)d_ws;
    size_t need = 0;
    auto alloc = [&](size_t bytes) {
        void* q = p;
        size_t pad = (bytes + 255) & ~(size_t)255;
        p += pad; need += pad;
        return q;
    };
    float* xcat   = (float*)alloc((size_t)N * 512 * 4);  // x1 | x2
    float* x3     = (float*)alloc((size_t)N * 256 * 4);
    int*   degs   = (int*)alloc((size_t)4 * N * 4);      // deg_in|deg_out|cur1|cur2
    int*   off1   = (int*)alloc((size_t)(N + 1) * 4);
    int*   off2   = (int*)alloc((size_t)(N + 1) * 4);
    int*   src1   = (int*)alloc((size_t)E * 4);
    int*   src2   = (int*)alloc((size_t)E * 4);
    float* w1s    = (float*)alloc((size_t)E * 4);
    float* w2s    = (float*)alloc((size_t)E * 4);
    int*   bs1    = (int*)alloc(1024 * 4);
    int*   bs2    = (int*)alloc(1024 * 4);
    if (need > ws_size) return;  // fail loudly (validation) rather than corrupt

    int* deg_in = degs, *deg_out = degs + N, *cur1 = degs + 2 * N, *cur2 = degs + 3 * N;

    hipMemsetAsync(degs, 0, (size_t)4 * N * 4, stream);

    const int eb = (E + 255) / 256;
    const int nb = (N + 255) / 256;
    deg_kernel<<<eb, 256, 0, stream>>>(ei, E, deg_in, deg_out);
    block_sums2<<<nb, 256, 0, stream>>>(deg_in, deg_out, N, bs1, bs2);
    scan_small2<<<1, 512, 0, stream>>>(bs1, bs2, nb);
    scan_final2<<<nb, 256, 0, stream>>>(deg_in, deg_out, bs1, bs2, N, off1, off2);
    fill_kernel<<<eb, 256, 0, stream>>>(ei, E, deg_in, deg_out, off1, off2,
                                        cur1, cur2, src1, w1s, src2, w2s, c1, c2);

    dim3 gg((N + BM - 1) / BM, 256 / BN);
    // x1 = x @ W1 -> xcat[:, 0:256]
    sgemm128<<<gg, 256, 0, stream>>>(x, 512, W1, 256, xcat, 512, N, 512);
    // x2 = mish(mish(conv1(x1))) -> xcat[:, 256:512]
    aggregate1<<<(N + 3) / 4, 256, 0, stream>>>(xcat, off1, src1, w1s, xcat, N);
    // x3 = [x1|x2] @ W2
    sgemm128<<<gg, 256, 0, stream>>>(xcat, 512, W2, 256, x3, 256, N, 512);
    // x4 + final fuse -> out
    aggregate2<<<(N + 3) / 4, 256, 0, stream>>>(x3, off2, src2, w2s, xcat, out, N);
}

// Round 2
// 1358.275 us; speedup vs baseline: 1.1620x; 1.1620x over previous
//
#include <hip/hip_runtime.h>
#include <math.h>

// ---------------------------------------------------------------------------
// SourceGCNConvEncoder on MI355X.
// x1 = x@W1 ; x2 = mish(mish(conv1(x1))) ; x3 = [x1|x2]@W2 ;
// x4 = mish(mish(conv2_rev(x3))) ; out = mish(x1+x2+x4)
// ---------------------------------------------------------------------------

// fast mish: tanh(softplus(x)) = ((1+e^x)^2 - 1) / ((1+e^x)^2 + 1)
// clamp x<=30 so (1+e^x)^2 <= e^60 ~ 1.1e26 (no overflow); for x>=30 the
// ratio is exactly 1.0f in fp32 so mish(x)=x, matching the true asymptote.
__device__ __forceinline__ float mishf(float x) {
    float e  = __expf(fminf(x, 30.0f));
    float u  = 1.0f + e;
    float u2 = u * u;
    return x * (u2 - 1.0f) * __builtin_amdgcn_rcpf(u2 + 1.0f);
}
__device__ __forceinline__ float mish2f(float x) { return mishf(mishf(x)); }

// ---- degrees ---------------------------------------------------------------
__global__ void deg_kernel(const int* __restrict__ ei, int E,
                           int* __restrict__ deg_in, int* __restrict__ deg_out) {
    int e = blockIdx.x * blockDim.x + threadIdx.x;
    if (e < E) {
        atomicAdd(&deg_out[ei[e]], 1);     // row
        atomicAdd(&deg_in[ei[E + e]], 1);  // col
    }
}

// ---- 3-pass dual exclusive scan over N elems -------------------------------
__global__ void block_sums2(const int* __restrict__ a, const int* __restrict__ b,
                            int n, int* __restrict__ bsa, int* __restrict__ bsb) {
    __shared__ int sa[256], sb[256];
    int t = threadIdx.x;
    int i = blockIdx.x * 256 + t;
    sa[t] = (i < n) ? a[i] : 0;
    sb[t] = (i < n) ? b[i] : 0;
    __syncthreads();
    for (int s = 128; s > 0; s >>= 1) {
        if (t < s) { sa[t] += sa[t + s]; sb[t] += sb[t + s]; }
        __syncthreads();
    }
    if (t == 0) { bsa[blockIdx.x] = sa[0]; bsb[blockIdx.x] = sb[0]; }
}

__global__ void scan_small2(int* __restrict__ bsa, int* __restrict__ bsb, int nb) {
    __shared__ int sa[512], sb[512];
    int t = threadIdx.x;
    int va = (t < nb) ? bsa[t] : 0;
    int vb = (t < nb) ? bsb[t] : 0;
    sa[t] = va; sb[t] = vb;
    __syncthreads();
    for (int off = 1; off < 512; off <<= 1) {
        int xa = (t >= off) ? sa[t - off] : 0;
        int xb = (t >= off) ? sb[t - off] : 0;
        __syncthreads();
        sa[t] += xa; sb[t] += xb;
        __syncthreads();
    }
    if (t < nb) { bsa[t] = sa[t] - va; bsb[t] = sb[t] - vb; }  // exclusive
}

__global__ void scan_final2(const int* __restrict__ a, const int* __restrict__ b,
                            const int* __restrict__ bsa, const int* __restrict__ bsb,
                            int n, int* __restrict__ offa, int* __restrict__ offb) {
    __shared__ int sa[256], sb[256];
    int t = threadIdx.x;
    int i = blockIdx.x * 256 + t;
    int va = (i < n) ? a[i] : 0;
    int vb = (i < n) ? b[i] : 0;
    sa[t] = va; sb[t] = vb;
    __syncthreads();
    for (int off = 1; off < 256; off <<= 1) {
        int xa = (t >= off) ? sa[t - off] : 0;
        int xb = (t >= off) ? sb[t - off] : 0;
        __syncthreads();
        sa[t] += xa; sb[t] += xb;
        __syncthreads();
    }
    if (i < n) {
        offa[i] = bsa[blockIdx.x] + sa[t] - va;
        offb[i] = bsb[blockIdx.x] + sb[t] - vb;
        if (i == n - 1) {
            offa[n] = bsa[blockIdx.x] + sa[t];
            offb[n] = bsb[blockIdx.x] + sb[t];
        }
    }
}

// ---- CSR fill with per-edge norms ------------------------------------------
__global__ void fill_kernel(const int* __restrict__ ei, int E,
                            const int* __restrict__ deg_in, const int* __restrict__ deg_out,
                            const int* __restrict__ off1, const int* __restrict__ off2,
                            int* __restrict__ cur1, int* __restrict__ cur2,
                            int* __restrict__ src1, float* __restrict__ w1s,
                            int* __restrict__ src2, float* __restrict__ w2s,
                            const float* __restrict__ c1p, const float* __restrict__ c2p) {
    int e = blockIdx.x * blockDim.x + threadIdx.x;
    if (e >= E) return;
    int r = ei[e], c = ei[E + e];
    float din  = (float)deg_in[c];   // >=1 for existing edge
    float dout = (float)deg_out[r];  // >=1
    float invs = 1.0f / (din + dout);
    float n1 = c1p[0] * invs + 1.0f / din;   // conv1: aggregate at col, msg from row
    float n2 = c2p[0] * invs + 1.0f / dout;  // conv2(rev): aggregate at row, msg from col
    int p1 = off1[c] + atomicAdd(&cur1[c], 1);
    src1[p1] = r; w1s[p1] = n1;
    int p2 = off2[r] + atomicAdd(&cur2[r], 1);
    src2[p2] = c; w2s[p2] = n2;
}

// ---- fp32 GEMM: C[M,256] = A[M,K]*B[K,256]; 64x256 tile, 8x8/thread --------
// As stored transposed + XOR-swizzled: phys = k*64 + (m ^ (k & 28)).
// Write banks: (m ^ 4*c4) -> exactly 2 lanes/bank (free). Reads stay 16B-
// aligned float4 since the XOR value is a multiple of 4.
#define GBM 64
#define GBK 32
#define GBN 256
__launch_bounds__(256)
__global__ void sgemm_n256(const float* __restrict__ A, int lda,
                           const float* __restrict__ B, int ldb,
                           float* __restrict__ C, int ldc,
                           int M, int K) {
    __shared__ float As[GBK * GBM];   // 8 KB, swizzled transpose
    __shared__ float Bs[GBK * GBN];   // 32 KB, row-major [k][n]
    const int tid = threadIdx.x;
    const int bm  = blockIdx.x * GBM;
    const int tx8 = (tid & 31) * 8;   // output col base
    const int ty8 = (tid >> 5) * 8;   // output row base

    const int arow = tid >> 3;        // A-load row 0..31 (+32)
    const int acol = (tid & 7) * 4;   // A-load k base; == swizzle xk for these 4 k
    const int brow = tid >> 6;        // B-load row 0..3 (+4 per round)
    const int bcol = (tid & 63) * 4;  // B-load col

    float acc[8][8];
#pragma unroll
    for (int i = 0; i < 8; ++i)
#pragma unroll
        for (int j = 0; j < 8; ++j) acc[i][j] = 0.f;

    for (int k0 = 0; k0 < K; k0 += GBK) {
#pragma unroll
        for (int r = 0; r < 2; ++r) {
            int m = r * 32 + arow;
            int grow = bm + m; grow = grow < M ? grow : M - 1;  // clamp; stores guarded
            const float4 v = *(const float4*)(A + (size_t)grow * lda + k0 + acol);
            int pm = m ^ acol;
            As[((acol + 0) << 6) + pm] = v.x;
            As[((acol + 1) << 6) + pm] = v.y;
            As[((acol + 2) << 6) + pm] = v.z;
            As[((acol + 3) << 6) + pm] = v.w;
        }
#pragma unroll
        for (int r = 0; r < 8; ++r) {
            int kr = r * 4 + brow;
            *(float4*)&Bs[(kr << 8) + bcol] =
                *(const float4*)(B + (size_t)(k0 + kr) * ldb + bcol);
        }
        __syncthreads();
#pragma unroll 8
        for (int k = 0; k < GBK; ++k) {
            int p0 = (k << 6) + (ty8 ^ (k & 28));
            float4 a0 = *(const float4*)&As[p0];
            float4 a1 = *(const float4*)&As[p0 ^ 4];
            float4 b0 = *(const float4*)&Bs[(k << 8) + tx8];
            float4 b1 = *(const float4*)&Bs[(k << 8) + tx8 + 4];
            float av[8] = {a0.x, a0.y, a0.z, a0.w, a1.x, a1.y, a1.z, a1.w};
            float bv[8] = {b0.x, b0.y, b0.z, b0.w, b1.x, b1.y, b1.z, b1.w};
#pragma unroll
            for (int i = 0; i < 8; ++i)
#pragma unroll
                for (int j = 0; j < 8; ++j)
                    acc[i][j] = fmaf(av[i], bv[j], acc[i][j]);
        }
        __syncthreads();
    }
#pragma unroll
    for (int i = 0; i < 8; ++i) {
        int row = bm + ty8 + i;
        if (row < M) {
            *(float4*)(C + (size_t)row * ldc + tx8) =
                make_float4(acc[i][0], acc[i][1], acc[i][2], acc[i][3]);
            *(float4*)(C + (size_t)row * ldc + tx8 + 4) =
                make_float4(acc[i][4], acc[i][5], acc[i][6], acc[i][7]);
        }
    }
}

// ---- conv1 aggregation: x2 = mish(mish(sum norm1 * x1[src])) ---------------
// x1 lives in xcat cols [0,256); x2 written to xcat cols [256,512)
__global__ void aggregate1(const float* __restrict__ xcat,
                           const int* __restrict__ off, const int* __restrict__ src,
                           const float* __restrict__ wgt,
                           float* __restrict__ xcat_out, int n) {
    int node = blockIdx.x * 4 + (threadIdx.x >> 6);
    int lane = threadIdx.x & 63;
    if (node >= n) return;
    int s0 = off[node], s1 = off[node + 1];
    float ax = 0.f, ay = 0.f, az = 0.f, aw = 0.f;
    for (int j = s0; j < s1; ++j) {
        int s = src[j];
        float w = wgt[j];
        const float4 v = *(const float4*)(xcat + (size_t)s * 512 + lane * 4);
        ax = fmaf(w, v.x, ax); ay = fmaf(w, v.y, ay);
        az = fmaf(w, v.z, az); aw = fmaf(w, v.w, aw);
    }
    float4 o = make_float4(mish2f(ax), mish2f(ay), mish2f(az), mish2f(aw));
    *(float4*)(xcat_out + (size_t)node * 512 + 256 + lane * 4) = o;
}

// ---- conv2 aggregation + final fuse: out = mish(x1+x2+mish(mish(agg))) -----
__global__ void aggregate2(const float* __restrict__ x3,
                           const int* __restrict__ off, const int* __restrict__ src,
                           const float* __restrict__ wgt,
                           const float* __restrict__ xcat,
                           float* __restrict__ out, int n) {
    int node = blockIdx.x * 4 + (threadIdx.x >> 6);
    int lane = threadIdx.x & 63;
    if (node >= n) return;
    int s0 = off[node], s1 = off[node + 1];
    float ax = 0.f, ay = 0.f, az = 0.f, aw = 0.f;
    for (int j = s0; j < s1; ++j) {
        int s = src[j];
        float w = wgt[j];
        const float4 v = *(const float4*)(x3 + (size_t)s * 256 + lane * 4);
        ax = fmaf(w, v.x, ax); ay = fmaf(w, v.y, ay);
        az = fmaf(w, v.z, az); aw = fmaf(w, v.w, aw);
    }
    const float4 x1v = *(const float4*)(xcat + (size_t)node * 512 + lane * 4);
    const float4 x2v = *(const float4*)(xcat + (size_t)node * 512 + 256 + lane * 4);
    float4 o;
    o.x = mishf(x1v.x + x2v.x + mish2f(ax));
    o.y = mishf(x1v.y + x2v.y + mish2f(ay));
    o.z = mishf(x1v.z + x2v.z + mish2f(az));
    o.w = mishf(x1v.w + x2v.w + mish2f(aw));
    *(float4*)(out + (size_t)node * 256 + lane * 4) = o;
}

// ---------------------------------------------------------------------------
extern "C" void kernel_launch(void* const* d_in, const int* in_sizes, int n_in,
                              void* d_out, int out_size, void* d_ws, size_t ws_size,
                              hipStream_t stream) {
    const float* x  = (const float*)d_in[0];
    const int*   ei = (const int*)d_in[1];
    const float* W1 = (const float*)d_in[2];
    const float* W2 = (const float*)d_in[3];
    const float* c1 = (const float*)d_in[4];
    const float* c2 = (const float*)d_in[5];
    float* out = (float*)d_out;

    const int N = in_sizes[0] / 512;  // 100000
    const int E = in_sizes[1] / 2;    // 800000

    // workspace carve-up (256B aligned)
    char* p = (char*)d_ws;
    size_t need = 0;
    auto alloc = [&](size_t bytes) {
        void* q = p;
        size_t pad = (bytes + 255) & ~(size_t)255;
        p += pad; need += pad;
        return q;
    };
    float* xcat   = (float*)alloc((size_t)N * 512 * 4);  // x1 | x2
    float* x3     = (float*)alloc((size_t)N * 256 * 4);
    int*   degs   = (int*)alloc((size_t)4 * N * 4);      // deg_in|deg_out|cur1|cur2
    int*   off1   = (int*)alloc((size_t)(N + 1) * 4);
    int*   off2   = (int*)alloc((size_t)(N + 1) * 4);
    int*   src1   = (int*)alloc((size_t)E * 4);
    int*   src2   = (int*)alloc((size_t)E * 4);
    float* w1s    = (float*)alloc((size_t)E * 4);
    float* w2s    = (float*)alloc((size_t)E * 4);
    int*   bs1    = (int*)alloc(1024 * 4);
    int*   bs2    = (int*)alloc(1024 * 4);
    if (need > ws_size) return;

    int* deg_in = degs, *deg_out = degs + N, *cur1 = degs + 2 * N, *cur2 = degs + 3 * N;

    hipMemsetAsync(degs, 0, (size_t)4 * N * 4, stream);

    const int eb = (E + 255) / 256;
    const int nb = (N + 255) / 256;
    deg_kernel<<<eb, 256, 0, stream>>>(ei, E, deg_in, deg_out);
    block_sums2<<<nb, 256, 0, stream>>>(deg_in, deg_out, N, bs1, bs2);
    scan_small2<<<1, 512, 0, stream>>>(bs1, bs2, nb);
    scan_final2<<<nb, 256, 0, stream>>>(deg_in, deg_out, bs1, bs2, N, off1, off2);
    fill_kernel<<<eb, 256, 0, stream>>>(ei, E, deg_in, deg_out, off1, off2,
                                        cur1, cur2, src1, w1s, src2, w2s, c1, c2);

    const int gblocks = (N + GBM - 1) / GBM;
    // x1 = x @ W1 -> xcat[:, 0:256]
    sgemm_n256<<<gblocks, 256, 0, stream>>>(x, 512, W1, 256, xcat, 512, N, 512);
    // x2 = mish(mish(conv1(x1))) -> xcat[:, 256:512]
    aggregate1<<<(N + 3) / 4, 256, 0, stream>>>(xcat, off1, src1, w1s, xcat, N);
    // x3 = [x1|x2] @ W2
    sgemm_n256<<<gblocks, 256, 0, stream>>>(xcat, 512, W2, 256, x3, 256, N, 512);
    // x4 + final fuse -> out
    aggregate2<<<(N + 3) / 4, 256, 0, stream>>>(x3, off2, src2, w2s, xcat, out, N);
}

// Round 4
// 1332.281 us; speedup vs baseline: 1.1846x; 1.0195x over previous
//
#include <hip/hip_runtime.h>
#include <math.h>

// ---------------------------------------------------------------------------
// SourceGCNConvEncoder on MI355X.
// x1 = x@W1 ; x2 = mish(mish(conv1(x1))) ; x3 = [x1|x2]@W2 ;
// x4 = mish(mish(conv2_rev(x3))) ; out = mish(x1+x2+x4)
// ---------------------------------------------------------------------------

// fast mish: tanh(softplus(x)) = ((1+e^x)^2 - 1) / ((1+e^x)^2 + 1)
__device__ __forceinline__ float mishf(float x) {
    float e  = __expf(fminf(x, 30.0f));
    float u  = 1.0f + e;
    float u2 = u * u;
    return x * (u2 - 1.0f) * __builtin_amdgcn_rcpf(u2 + 1.0f);
}
__device__ __forceinline__ float mish2f(float x) { return mishf(mishf(x)); }

// ---- degrees ---------------------------------------------------------------
__global__ void deg_kernel(const int* __restrict__ ei, int E,
                           int* __restrict__ deg_in, int* __restrict__ deg_out) {
    int e = blockIdx.x * blockDim.x + threadIdx.x;
    if (e < E) {
        atomicAdd(&deg_out[ei[e]], 1);     // row
        atomicAdd(&deg_in[ei[E + e]], 1);  // col
    }
}

// ---- 3-pass dual exclusive scan over N elems -------------------------------
__global__ void block_sums2(const int* __restrict__ a, const int* __restrict__ b,
                            int n, int* __restrict__ bsa, int* __restrict__ bsb) {
    __shared__ int sa[256], sb[256];
    int t = threadIdx.x;
    int i = blockIdx.x * 256 + t;
    sa[t] = (i < n) ? a[i] : 0;
    sb[t] = (i < n) ? b[i] : 0;
    __syncthreads();
    for (int s = 128; s > 0; s >>= 1) {
        if (t < s) { sa[t] += sa[t + s]; sb[t] += sb[t + s]; }
        __syncthreads();
    }
    if (t == 0) { bsa[blockIdx.x] = sa[0]; bsb[blockIdx.x] = sb[0]; }
}

__global__ void scan_small2(int* __restrict__ bsa, int* __restrict__ bsb, int nb) {
    __shared__ int sa[512], sb[512];
    int t = threadIdx.x;
    int va = (t < nb) ? bsa[t] : 0;
    int vb = (t < nb) ? bsb[t] : 0;
    sa[t] = va; sb[t] = vb;
    __syncthreads();
    for (int off = 1; off < 512; off <<= 1) {
        int xa = (t >= off) ? sa[t - off] : 0;
        int xb = (t >= off) ? sb[t - off] : 0;
        __syncthreads();
        sa[t] += xa; sb[t] += xb;
        __syncthreads();
    }
    if (t < nb) { bsa[t] = sa[t] - va; bsb[t] = sb[t] - vb; }  // exclusive
}

__global__ void scan_final2(const int* __restrict__ a, const int* __restrict__ b,
                            const int* __restrict__ bsa, const int* __restrict__ bsb,
                            int n, int* __restrict__ offa, int* __restrict__ offb) {
    __shared__ int sa[256], sb[256];
    int t = threadIdx.x;
    int i = blockIdx.x * 256 + t;
    int va = (i < n) ? a[i] : 0;
    int vb = (i < n) ? b[i] : 0;
    sa[t] = va; sb[t] = vb;
    __syncthreads();
    for (int off = 1; off < 256; off <<= 1) {
        int xa = (t >= off) ? sa[t - off] : 0;
        int xb = (t >= off) ? sb[t - off] : 0;
        __syncthreads();
        sa[t] += xa; sb[t] += xb;
        __syncthreads();
    }
    if (i < n) {
        offa[i] = bsa[blockIdx.x] + sa[t] - va;
        offb[i] = bsb[blockIdx.x] + sb[t] - vb;
        if (i == n - 1) {
            offa[n] = bsa[blockIdx.x] + sa[t];
            offb[n] = bsb[blockIdx.x] + sb[t];
        }
    }
}

// ---- CSR fill: packed (src, weight) per edge per direction ------------------
__global__ void fill_kernel(const int* __restrict__ ei, int E,
                            const int* __restrict__ deg_in, const int* __restrict__ deg_out,
                            const int* __restrict__ off1, const int* __restrict__ off2,
                            int* __restrict__ cur1, int* __restrict__ cur2,
                            int2* __restrict__ ed1, int2* __restrict__ ed2,
                            const float* __restrict__ c1p, const float* __restrict__ c2p) {
    int e = blockIdx.x * blockDim.x + threadIdx.x;
    if (e >= E) return;
    int r = ei[e], c = ei[E + e];
    float din  = (float)deg_in[c];   // >=1 for existing edge
    float dout = (float)deg_out[r];  // >=1
    float invs = 1.0f / (din + dout);
    float n1 = c1p[0] * invs + 1.0f / din;   // conv1: aggregate at col, msg from row
    float n2 = c2p[0] * invs + 1.0f / dout;  // conv2(rev): aggregate at row, msg from col
    int p1 = off1[c] + atomicAdd(&cur1[c], 1);
    ed1[p1] = make_int2(r, __float_as_int(n1));
    int p2 = off2[r] + atomicAdd(&cur2[r], 1);
    ed2[p2] = make_int2(c, __float_as_int(n2));
}

// ---- fp32 GEMM: C[M,:] tile 128x128, BK=16, 8x8/thread (split 4+4) ---------
// A comes from two row-major sources: rows of A0 (k < ksplit, lda0) then A1.
// As transposed, stride 132: store bank = (4k+row)%32 -> 2-way (free); reads
// broadcast. B fragments at tx*4 and tx*4+64 -> 2-way banks (free).
__launch_bounds__(256)
__global__ void sgemm_t128(const float* __restrict__ A0, int lda0,
                           const float* __restrict__ A1, int lda1, int ksplit,
                           const float* __restrict__ B, int ldb,
                           float* __restrict__ C, int ldc,
                           int M, int K) {
    __shared__ float As[16][132];  // 8.25 KB
    __shared__ float Bs[16][128];  // 8 KB
    const int tid = threadIdx.x;
    const int bm  = blockIdx.x * 128;
    const int bn  = blockIdx.y * 128;
    const int tx4 = (tid & 15) * 4;
    const int ty4 = ((tid >> 4) & 15) * 4;

    const int arow = tid & 127;        // A stage: row in tile
    const int ak8  = (tid >> 7) * 8;   // A stage: k base (0 or 8)
    const int bk   = tid >> 5;         // B stage: k row 0..7 (+8)
    const int bc4  = (tid & 31) * 4;   // B stage: col

    int grow = bm + arow;
    if (grow >= M) grow = M - 1;       // clamp; stores guarded

    float acc[8][8];
#pragma unroll
    for (int i = 0; i < 8; ++i)
#pragma unroll
        for (int j = 0; j < 8; ++j) acc[i][j] = 0.f;

    for (int k0 = 0; k0 < K; k0 += 16) {
        // stage A (transposed into As[k][row])
        const float* Ap = (k0 < ksplit)
            ? A0 + (size_t)grow * lda0 + k0
            : A1 + (size_t)grow * lda1 + (k0 - ksplit);
        const float4 va0 = *(const float4*)(Ap + ak8);
        const float4 va1 = *(const float4*)(Ap + ak8 + 4);
        As[ak8 + 0][arow] = va0.x;
        As[ak8 + 1][arow] = va0.y;
        As[ak8 + 2][arow] = va0.z;
        As[ak8 + 3][arow] = va0.w;
        As[ak8 + 4][arow] = va1.x;
        As[ak8 + 5][arow] = va1.y;
        As[ak8 + 6][arow] = va1.z;
        As[ak8 + 7][arow] = va1.w;
        // stage B
#pragma unroll
        for (int r = 0; r < 2; ++r) {
            int kr = bk + r * 8;
            *(float4*)&Bs[kr][bc4] =
                *(const float4*)(B + (size_t)(k0 + kr) * ldb + bn + bc4);
        }
        __syncthreads();
#pragma unroll
        for (int k = 0; k < 16; ++k) {
            const float4 a0 = *(const float4*)&As[k][ty4];
            const float4 a1 = *(const float4*)&As[k][ty4 + 64];
            const float4 b0 = *(const float4*)&Bs[k][tx4];
            const float4 b1 = *(const float4*)&Bs[k][tx4 + 64];
            float av[8] = {a0.x, a0.y, a0.z, a0.w, a1.x, a1.y, a1.z, a1.w};
            float bv[8] = {b0.x, b0.y, b0.z, b0.w, b1.x, b1.y, b1.z, b1.w};
#pragma unroll
            for (int i = 0; i < 8; ++i)
#pragma unroll
                for (int j = 0; j < 8; ++j)
                    acc[i][j] = fmaf(av[i], bv[j], acc[i][j]);
        }
        __syncthreads();
    }
#pragma unroll
    for (int i = 0; i < 8; ++i) {
        int r = (i < 4) ? (ty4 + i) : (64 + ty4 + i - 4);
        int row = bm + r;
        if (row < M) {
            *(float4*)(C + (size_t)row * ldc + bn + tx4) =
                make_float4(acc[i][0], acc[i][1], acc[i][2], acc[i][3]);
            *(float4*)(C + (size_t)row * ldc + bn + 64 + tx4) =
                make_float4(acc[i][4], acc[i][5], acc[i][6], acc[i][7]);
        }
    }
}

// ---- conv1 aggregation: x2 = mish(mish(sum w * x1[src])), 4-deep unroll ----
__global__ void aggregate1(const float* __restrict__ x1,
                           const int* __restrict__ off, const int2* __restrict__ ed,
                           float* __restrict__ x2, int n) {
    int node = blockIdx.x * 4 + (threadIdx.x >> 6);
    int lane = threadIdx.x & 63;
    if (node >= n) return;
    int s0 = off[node], s1 = off[node + 1];
    float ax = 0.f, ay = 0.f, az = 0.f, aw = 0.f;
    int j = s0;
    for (; j + 4 <= s1; j += 4) {
        int2 e0 = ed[j], e1 = ed[j + 1], e2 = ed[j + 2], e3 = ed[j + 3];
        const float4 v0 = *(const float4*)(x1 + (size_t)e0.x * 256 + lane * 4);
        const float4 v1 = *(const float4*)(x1 + (size_t)e1.x * 256 + lane * 4);
        const float4 v2 = *(const float4*)(x1 + (size_t)e2.x * 256 + lane * 4);
        const float4 v3 = *(const float4*)(x1 + (size_t)e3.x * 256 + lane * 4);
        float w0 = __int_as_float(e0.y), w1 = __int_as_float(e1.y);
        float w2 = __int_as_float(e2.y), w3 = __int_as_float(e3.y);
        ax = fmaf(w0, v0.x, ax); ay = fmaf(w0, v0.y, ay); az = fmaf(w0, v0.z, az); aw = fmaf(w0, v0.w, aw);
        ax = fmaf(w1, v1.x, ax); ay = fmaf(w1, v1.y, ay); az = fmaf(w1, v1.z, az); aw = fmaf(w1, v1.w, aw);
        ax = fmaf(w2, v2.x, ax); ay = fmaf(w2, v2.y, ay); az = fmaf(w2, v2.z, az); aw = fmaf(w2, v2.w, aw);
        ax = fmaf(w3, v3.x, ax); ay = fmaf(w3, v3.y, ay); az = fmaf(w3, v3.z, az); aw = fmaf(w3, v3.w, aw);
    }
    for (; j < s1; ++j) {
        int2 e = ed[j];
        float w = __int_as_float(e.y);
        const float4 v = *(const float4*)(x1 + (size_t)e.x * 256 + lane * 4);
        ax = fmaf(w, v.x, ax); ay = fmaf(w, v.y, ay);
        az = fmaf(w, v.z, az); aw = fmaf(w, v.w, aw);
    }
    float4 o = make_float4(mish2f(ax), mish2f(ay), mish2f(az), mish2f(aw));
    *(float4*)(x2 + (size_t)node * 256 + lane * 4) = o;
}

// ---- conv2 aggregation + final fuse: out = mish(x1+x2+mish(mish(agg))) -----
__global__ void aggregate2(const float* __restrict__ x3,
                           const int* __restrict__ off, const int2* __restrict__ ed,
                           const float* __restrict__ x1, const float* __restrict__ x2,
                           float* __restrict__ out, int n) {
    int node = blockIdx.x * 4 + (threadIdx.x >> 6);
    int lane = threadIdx.x & 63;
    if (node >= n) return;
    int s0 = off[node], s1 = off[node + 1];
    float ax = 0.f, ay = 0.f, az = 0.f, aw = 0.f;
    int j = s0;
    for (; j + 4 <= s1; j += 4) {
        int2 e0 = ed[j], e1 = ed[j + 1], e2 = ed[j + 2], e3 = ed[j + 3];
        const float4 v0 = *(const float4*)(x3 + (size_t)e0.x * 256 + lane * 4);
        const float4 v1 = *(const float4*)(x3 + (size_t)e1.x * 256 + lane * 4);
        const float4 v2 = *(const float4*)(x3 + (size_t)e2.x * 256 + lane * 4);
        const float4 v3 = *(const float4*)(x3 + (size_t)e3.x * 256 + lane * 4);
        float w0 = __int_as_float(e0.y), w1 = __int_as_float(e1.y);
        float w2 = __int_as_float(e2.y), w3 = __int_as_float(e3.y);
        ax = fmaf(w0, v0.x, ax); ay = fmaf(w0, v0.y, ay); az = fmaf(w0, v0.z, az); aw = fmaf(w0, v0.w, aw);
        ax = fmaf(w1, v1.x, ax); ay = fmaf(w1, v1.y, ay); az = fmaf(w1, v1.z, az); aw = fmaf(w1, v1.w, aw);
        ax = fmaf(w2, v2.x, ax); ay = fmaf(w2, v2.y, ay); az = fmaf(w2, v2.z, az); aw = fmaf(w2, v2.w, aw);
        ax = fmaf(w3, v3.x, ax); ay = fmaf(w3, v3.y, ay); az = fmaf(w3, v3.z, az); aw = fmaf(w3, v3.w, aw);
    }
    for (; j < s1; ++j) {
        int2 e = ed[j];
        float w = __int_as_float(e.y);
        const float4 v = *(const float4*)(x3 + (size_t)e.x * 256 + lane * 4);
        ax = fmaf(w, v.x, ax); ay = fmaf(w, v.y, ay);
        az = fmaf(w, v.z, az); aw = fmaf(w, v.w, aw);
    }
    const float4 x1v = *(const float4*)(x1 + (size_t)node * 256 + lane * 4);
    const float4 x2v = *(const float4*)(x2 + (size_t)node * 256 + lane * 4);
    float4 o;
    o.x = mishf(x1v.x + x2v.x + mish2f(ax));
    o.y = mishf(x1v.y + x2v.y + mish2f(ay));
    o.z = mishf(x1v.z + x2v.z + mish2f(az));
    o.w = mishf(x1v.w + x2v.w + mish2f(aw));
    *(float4*)(out + (size_t)node * 256 + lane * 4) = o;
}

// ---------------------------------------------------------------------------
extern "C" void kernel_launch(void* const* d_in, const int* in_sizes, int n_in,
                              void* d_out, int out_size, void* d_ws, size_t ws_size,
                              hipStream_t stream) {
    const float* x  = (const float*)d_in[0];
    const int*   ei = (const int*)d_in[1];
    const float* W1 = (const float*)d_in[2];
    const float* W2 = (const float*)d_in[3];
    const float* c1 = (const float*)d_in[4];
    const float* c2 = (const float*)d_in[5];
    float* out = (float*)d_out;

    const int N = in_sizes[0] / 512;  // 100000
    const int E = in_sizes[1] / 2;    // 800000

    // workspace carve-up (256B aligned)
    char* p = (char*)d_ws;
    size_t need = 0;
    auto alloc = [&](size_t bytes) {
        void* q = p;
        size_t pad = (bytes + 255) & ~(size_t)255;
        p += pad; need += pad;
        return q;
    };
    float* x1    = (float*)alloc((size_t)N * 256 * 4);
    float* x2    = (float*)alloc((size_t)N * 256 * 4);
    float* x3    = (float*)alloc((size_t)N * 256 * 4);
    int*   degs  = (int*)alloc((size_t)4 * N * 4);      // deg_in|deg_out|cur1|cur2
    int*   off1  = (int*)alloc((size_t)(N + 1) * 4);
    int*   off2  = (int*)alloc((size_t)(N + 1) * 4);
    int2*  ed1   = (int2*)alloc((size_t)E * 8);
    int2*  ed2   = (int2*)alloc((size_t)E * 8);
    int*   bs1   = (int*)alloc(1024 * 4);
    int*   bs2   = (int*)alloc(1024 * 4);
    if (need > ws_size) return;

    int* deg_in = degs, *deg_out = degs + N, *cur1 = degs + 2 * N, *cur2 = degs + 3 * N;

    hipMemsetAsync(degs, 0, (size_t)4 * N * 4, stream);

    const int eb = (E + 255) / 256;
    const int nb = (N + 255) / 256;
    deg_kernel<<<eb, 256, 0, stream>>>(ei, E, deg_in, deg_out);
    block_sums2<<<nb, 256, 0, stream>>>(deg_in, deg_out, N, bs1, bs2);
    scan_small2<<<1, 512, 0, stream>>>(bs1, bs2, nb);
    scan_final2<<<nb, 256, 0, stream>>>(deg_in, deg_out, bs1, bs2, N, off1, off2);
    fill_kernel<<<eb, 256, 0, stream>>>(ei, E, deg_in, deg_out, off1, off2,
                                        cur1, cur2, ed1, ed2, c1, c2);

    dim3 gg((N + 127) / 128, 2);
    // x1 = x @ W1
    sgemm_t128<<<gg, 256, 0, stream>>>(x, 512, x, 512, 512, W1, 256, x1, 256, N, 512);
    // x2 = mish(mish(conv1(x1)))
    aggregate1<<<(N + 3) / 4, 256, 0, stream>>>(x1, off1, ed1, x2, N);
    // x3 = [x1|x2] @ W2  (A split across the two compact halves)
    sgemm_t128<<<gg, 256, 0, stream>>>(x1, 256, x2, 256, 256, W2, 256, x3, 256, N, 512);
    // x4 + final fuse -> out
    aggregate2<<<(N + 3) / 4, 256, 0, stream>>>(x3, off2, ed2, x1, x2, out, N);
}

// Round 6
// 1127.109 us; speedup vs baseline: 1.4003x; 1.1820x over previous
//
#include <hip/hip_runtime.h>
#include <math.h>

// ---------------------------------------------------------------------------
// SourceGCNConvEncoder on MI355X.
// x1 = x@W1 ; x2 = mish(mish(conv1(x1))) ; x3 = [x1|x2]@W2 ;
// x4 = mish(mish(conv2_rev(x3))) ; out = mish(x1+x2+x4)
// GEMMs via bf16-split MFMA: C = Ah*Bh + Al*Bh + Ah*Bl  (one GEMM, K'=1536)
// ---------------------------------------------------------------------------

typedef short bf16x8 __attribute__((ext_vector_type(8)));
typedef float f32x4  __attribute__((ext_vector_type(4)));

// fast mish: tanh(softplus(x)) = ((1+e^x)^2 - 1) / ((1+e^x)^2 + 1)
__device__ __forceinline__ float mishf(float x) {
    float e  = __expf(fminf(x, 30.0f));
    float u  = 1.0f + e;
    float u2 = u * u;
    return x * (u2 - 1.0f) * __builtin_amdgcn_rcpf(u2 + 1.0f);
}
__device__ __forceinline__ float mish2f(float x) { return mishf(mishf(x)); }

__device__ __forceinline__ unsigned short bf16rne(float f) {
    unsigned u = __float_as_uint(f);
    unsigned r = u + 0x7FFFu + ((u >> 16) & 1u);
    return (unsigned short)(r >> 16);
}
__device__ __forceinline__ float bf16tof(unsigned short h) {
    return __uint_as_float((unsigned)h << 16);
}

// ---- degrees ---------------------------------------------------------------
__global__ void deg_kernel(const int* __restrict__ ei, int E,
                           int* __restrict__ deg_in, int* __restrict__ deg_out) {
    int e = blockIdx.x * blockDim.x + threadIdx.x;
    if (e < E) {
        atomicAdd(&deg_out[ei[e]], 1);     // row
        atomicAdd(&deg_in[ei[E + e]], 1);  // col
    }
}

// ---- 3-pass dual exclusive scan over N elems -------------------------------
__global__ void block_sums2(const int* __restrict__ a, const int* __restrict__ b,
                            int n, int* __restrict__ bsa, int* __restrict__ bsb) {
    __shared__ int sa[256], sb[256];
    int t = threadIdx.x;
    int i = blockIdx.x * 256 + t;
    sa[t] = (i < n) ? a[i] : 0;
    sb[t] = (i < n) ? b[i] : 0;
    __syncthreads();
    for (int s = 128; s > 0; s >>= 1) {
        if (t < s) { sa[t] += sa[t + s]; sb[t] += sb[t + s]; }
        __syncthreads();
    }
    if (t == 0) { bsa[blockIdx.x] = sa[0]; bsb[blockIdx.x] = sb[0]; }
}

__global__ void scan_small2(int* __restrict__ bsa, int* __restrict__ bsb, int nb) {
    __shared__ int sa[512], sb[512];
    int t = threadIdx.x;
    int va = (t < nb) ? bsa[t] : 0;
    int vb = (t < nb) ? bsb[t] : 0;
    sa[t] = va; sb[t] = vb;
    __syncthreads();
    for (int off = 1; off < 512; off <<= 1) {
        int xa = (t >= off) ? sa[t - off] : 0;
        int xb = (t >= off) ? sb[t - off] : 0;
        __syncthreads();
        sa[t] += xa; sb[t] += xb;
        __syncthreads();
    }
    if (t < nb) { bsa[t] = sa[t] - va; bsb[t] = sb[t] - vb; }  // exclusive
}

__global__ void scan_final2(const int* __restrict__ a, const int* __restrict__ b,
                            const int* __restrict__ bsa, const int* __restrict__ bsb,
                            int n, int* __restrict__ offa, int* __restrict__ offb) {
    __shared__ int sa[256], sb[256];
    int t = threadIdx.x;
    int i = blockIdx.x * 256 + t;
    int va = (i < n) ? a[i] : 0;
    int vb = (i < n) ? b[i] : 0;
    sa[t] = va; sb[t] = vb;
    __syncthreads();
    for (int off = 1; off < 256; off <<= 1) {
        int xa = (t >= off) ? sa[t - off] : 0;
        int xb = (t >= off) ? sb[t - off] : 0;
        __syncthreads();
        sa[t] += xa; sb[t] += xb;
        __syncthreads();
    }
    if (i < n) {
        offa[i] = bsa[blockIdx.x] + sa[t] - va;
        offb[i] = bsb[blockIdx.x] + sb[t] - vb;
        if (i == n - 1) {
            offa[n] = bsa[blockIdx.x] + sa[t];
            offb[n] = bsb[blockIdx.x] + sb[t];
        }
    }
}

// ---- CSR fill: packed (src, weight) per edge per direction ------------------
__global__ void fill_kernel(const int* __restrict__ ei, int E,
                            const int* __restrict__ deg_in, const int* __restrict__ deg_out,
                            const int* __restrict__ off1, const int* __restrict__ off2,
                            int* __restrict__ cur1, int* __restrict__ cur2,
                            int2* __restrict__ ed1, int2* __restrict__ ed2,
                            const float* __restrict__ c1p, const float* __restrict__ c2p) {
    int e = blockIdx.x * blockDim.x + threadIdx.x;
    if (e >= E) return;
    int r = ei[e], c = ei[E + e];
    float din  = (float)deg_in[c];   // >=1 for existing edge
    float dout = (float)deg_out[r];  // >=1
    float invs = 1.0f / (din + dout);
    float n1 = c1p[0] * invs + 1.0f / din;   // conv1: aggregate at col, msg from row
    float n2 = c2p[0] * invs + 1.0f / dout;  // conv2(rev): aggregate at row, msg from col
    int p1 = off1[c] + atomicAdd(&cur1[c], 1);
    ed1[p1] = make_int2(r, __float_as_int(n1));
    int p2 = off2[r] + atomicAdd(&cur2[r], 1);
    ed2[p2] = make_int2(c, __float_as_int(n2));
}

// ---- W transpose + bf16 hi/lo split: W[512][256] -> Wth/Wtl[256][512] ------
__global__ void split_w(const float* __restrict__ W1, const float* __restrict__ W2,
                        unsigned short* __restrict__ W1th, unsigned short* __restrict__ W1tl,
                        unsigned short* __restrict__ W2th, unsigned short* __restrict__ W2tl) {
    int id = blockIdx.x * 256 + threadIdx.x;     // 2*512*256 total
    int which = id >> 17;
    int rem = id & 131071;
    int n = rem >> 9;
    int k = rem & 511;
    const float* W = which ? W2 : W1;
    float f = W[k * 256 + n];
    unsigned short h = bf16rne(f);
    unsigned short l = bf16rne(f - bf16tof(h));
    (which ? W2th : W1th)[n * 512 + k] = h;
    (which ? W2tl : W1tl)[n * 512 + k] = l;
}

// ---- MFMA GEMM: C[M,256] = A[M,512]*W[512,256] via bf16 hi/lo, K'=1536 -----
// A' = [Ah | Al | Ah] in 256-col chunks: {A0h, A1h, A0l, A1l, A0h, A1h}
//   GEMM1: A0 = x, A1 = x+256 (lda=512);  GEMM2: A0 = x1, A1 = x2 (lda=256)
// B' = [Bh ; Bh ; Bl] chunks: {Wth, Wth+256, Wth, Wth+256, Wtl, Wtl+256}
// LDS rows padded to 40 bf16 (80B): bank-balanced for b128 writes and reads.
__launch_bounds__(256)
__global__ void gemm_bf16x3(const float* __restrict__ A0, const float* __restrict__ A1,
                            int lda,
                            const unsigned short* __restrict__ Wth,
                            const unsigned short* __restrict__ Wtl,
                            float* __restrict__ C, int M) {
    __shared__ unsigned short Asm[128 * 40];
    __shared__ unsigned short Bsm[128 * 40];
    const int tid  = threadIdx.x;
    const int bm   = blockIdx.x * 128;
    const int bn   = blockIdx.y * 128;
    const int lane = tid & 63;
    const int w    = tid >> 6;
    const int wr   = w >> 1, wc = w & 1;
    const int srow = tid >> 2;        // staging row 0..63 (+64)
    const int slot = tid & 3;         // 16B k-slot (8 bf16)
    const int l15  = lane & 15;
    const int l4   = lane >> 4;

    f32x4 acc[4][4];
#pragma unroll
    for (int i = 0; i < 4; ++i)
#pragma unroll
        for (int j = 0; j < 4; ++j) acc[i][j] = (f32x4){0.f, 0.f, 0.f, 0.f};

    for (int k0 = 0; k0 < 1536; k0 += 32) {
        const int s    = k0 >> 8;                 // 256-col chunk 0..5
        const int kloc = (k0 & 255) + slot * 8;
        const float* Ab = (s & 1) ? A1 : A0;
        const bool lo   = (s == 2) || (s == 3);
        const unsigned short* Bb = ((s < 4) ? Wth : Wtl) + (s & 1) * 256;
#pragma unroll
        for (int r = 0; r < 2; ++r) {
            const int m = srow + r * 64;
            int grow = bm + m; if (grow >= M) grow = M - 1;
            const float4 f0 = *(const float4*)(Ab + (size_t)grow * lda + kloc);
            const float4 f1 = *(const float4*)(Ab + (size_t)grow * lda + kloc + 4);
            float fv[8] = {f0.x, f0.y, f0.z, f0.w, f1.x, f1.y, f1.z, f1.w};
            bf16x8 v;
#pragma unroll
            for (int j = 0; j < 8; ++j) {
                unsigned short h = bf16rne(fv[j]);
                if (lo) h = bf16rne(fv[j] - bf16tof(h));
                v[j] = (short)h;
            }
            *(bf16x8*)&Asm[m * 40 + slot * 8] = v;
            // stage B^T row (contiguous bf16 k)
            const int n = srow + r * 64;
            const uint4 bw = *(const uint4*)(Bb + (size_t)(bn + n) * 512 + kloc);
            *(uint4*)&Bsm[n * 40 + slot * 8] = bw;
        }
        __syncthreads();
        bf16x8 af[4], bfr[4];
#pragma unroll
        for (int i = 0; i < 4; ++i) {
            af[i]  = *(const bf16x8*)&Asm[(wr * 64 + i * 16 + l15) * 40 + l4 * 8];
            bfr[i] = *(const bf16x8*)&Bsm[(wc * 64 + i * 16 + l15) * 40 + l4 * 8];
        }
#pragma unroll
        for (int i = 0; i < 4; ++i)
#pragma unroll
            for (int j = 0; j < 4; ++j)
                acc[i][j] = __builtin_amdgcn_mfma_f32_16x16x32_bf16(
                    af[i], bfr[j], acc[i][j], 0, 0, 0);
        __syncthreads();
    }
    // epilogue: C/D layout col = lane&15, row = (lane>>4)*4 + reg  [m89]
#pragma unroll
    for (int i = 0; i < 4; ++i) {
        const int row0 = bm + wr * 64 + i * 16 + l4 * 4;
#pragma unroll
        for (int j = 0; j < 4; ++j) {
            const int col = bn + wc * 64 + j * 16 + l15;
#pragma unroll
            for (int r = 0; r < 4; ++r) {
                const int row = row0 + r;
                if (row < M) C[(size_t)row * 256 + col] = acc[i][j][r];
            }
        }
    }
}

// ---- conv1 aggregation: x2 = mish(mish(sum w * x1[src])), 4-deep unroll ----
__global__ void aggregate1(const float* __restrict__ x1,
                           const int* __restrict__ off, const int2* __restrict__ ed,
                           float* __restrict__ x2, int n) {
    int node = blockIdx.x * 4 + (threadIdx.x >> 6);
    int lane = threadIdx.x & 63;
    if (node >= n) return;
    int s0 = off[node], s1 = off[node + 1];
    float ax = 0.f, ay = 0.f, az = 0.f, aw = 0.f;
    int j = s0;
    for (; j + 4 <= s1; j += 4) {
        int2 e0 = ed[j], e1 = ed[j + 1], e2 = ed[j + 2], e3 = ed[j + 3];
        const float4 v0 = *(const float4*)(x1 + (size_t)e0.x * 256 + lane * 4);
        const float4 v1 = *(const float4*)(x1 + (size_t)e1.x * 256 + lane * 4);
        const float4 v2 = *(const float4*)(x1 + (size_t)e2.x * 256 + lane * 4);
        const float4 v3 = *(const float4*)(x1 + (size_t)e3.x * 256 + lane * 4);
        float w0 = __int_as_float(e0.y), w1 = __int_as_float(e1.y);
        float w2 = __int_as_float(e2.y), w3 = __int_as_float(e3.y);
        ax = fmaf(w0, v0.x, ax); ay = fmaf(w0, v0.y, ay); az = fmaf(w0, v0.z, az); aw = fmaf(w0, v0.w, aw);
        ax = fmaf(w1, v1.x, ax); ay = fmaf(w1, v1.y, ay); az = fmaf(w1, v1.z, az); aw = fmaf(w1, v1.w, aw);
        ax = fmaf(w2, v2.x, ax); ay = fmaf(w2, v2.y, ay); az = fmaf(w2, v2.z, az); aw = fmaf(w2, v2.w, aw);
        ax = fmaf(w3, v3.x, ax); ay = fmaf(w3, v3.y, ay); az = fmaf(w3, v3.z, az); aw = fmaf(w3, v3.w, aw);
    }
    for (; j < s1; ++j) {
        int2 e = ed[j];
        float w = __int_as_float(e.y);
        const float4 v = *(const float4*)(x1 + (size_t)e.x * 256 + lane * 4);
        ax = fmaf(w, v.x, ax); ay = fmaf(w, v.y, ay);
        az = fmaf(w, v.z, az); aw = fmaf(w, v.w, aw);
    }
    float4 o = make_float4(mish2f(ax), mish2f(ay), mish2f(az), mish2f(aw));
    *(float4*)(x2 + (size_t)node * 256 + lane * 4) = o;
}

// ---- conv2 aggregation + final fuse: out = mish(x1+x2+mish(mish(agg))) -----
__global__ void aggregate2(const float* __restrict__ x3,
                           const int* __restrict__ off, const int2* __restrict__ ed,
                           const float* __restrict__ x1, const float* __restrict__ x2,
                           float* __restrict__ out, int n) {
    int node = blockIdx.x * 4 + (threadIdx.x >> 6);
    int lane = threadIdx.x & 63;
    if (node >= n) return;
    int s0 = off[node], s1 = off[node + 1];
    float ax = 0.f, ay = 0.f, az = 0.f, aw = 0.f;
    int j = s0;
    for (; j + 4 <= s1; j += 4) {
        int2 e0 = ed[j], e1 = ed[j + 1], e2 = ed[j + 2], e3 = ed[j + 3];
        const float4 v0 = *(const float4*)(x3 + (size_t)e0.x * 256 + lane * 4);
        const float4 v1 = *(const float4*)(x3 + (size_t)e1.x * 256 + lane * 4);
        const float4 v2 = *(const float4*)(x3 + (size_t)e2.x * 256 + lane * 4);
        const float4 v3 = *(const float4*)(x3 + (size_t)e3.x * 256 + lane * 4);
        float w0 = __int_as_float(e0.y), w1 = __int_as_float(e1.y);
        float w2 = __int_as_float(e2.y), w3 = __int_as_float(e3.y);
        ax = fmaf(w0, v0.x, ax); ay = fmaf(w0, v0.y, ay); az = fmaf(w0, v0.z, az); aw = fmaf(w0, v0.w, aw);
        ax = fmaf(w1, v1.x, ax); ay = fmaf(w1, v1.y, ay); az = fmaf(w1, v1.z, az); aw = fmaf(w1, v1.w, aw);
        ax = fmaf(w2, v2.x, ax); ay = fmaf(w2, v2.y, ay); az = fmaf(w2, v2.z, az); aw = fmaf(w2, v2.w, aw);
        ax = fmaf(w3, v3.x, ax); ay = fmaf(w3, v3.y, ay); az = fmaf(w3, v3.z, az); aw = fmaf(w3, v3.w, aw);
    }
    for (; j < s1; ++j) {
        int2 e = ed[j];
        float w = __int_as_float(e.y);
        const float4 v = *(const float4*)(x3 + (size_t)e.x * 256 + lane * 4);
        ax = fmaf(w, v.x, ax); ay = fmaf(w, v.y, ay);
        az = fmaf(w, v.z, az); aw = fmaf(w, v.w, aw);
    }
    const float4 x1v = *(const float4*)(x1 + (size_t)node * 256 + lane * 4);
    const float4 x2v = *(const float4*)(x2 + (size_t)node * 256 + lane * 4);
    float4 o;
    o.x = mishf(x1v.x + x2v.x + mish2f(ax));
    o.y = mishf(x1v.y + x2v.y + mish2f(ay));
    o.z = mishf(x1v.z + x2v.z + mish2f(az));
    o.w = mishf(x1v.w + x2v.w + mish2f(aw));
    *(float4*)(out + (size_t)node * 256 + lane * 4) = o;
}

// ---------------------------------------------------------------------------
extern "C" void kernel_launch(void* const* d_in, const int* in_sizes, int n_in,
                              void* d_out, int out_size, void* d_ws, size_t ws_size,
                              hipStream_t stream) {
    const float* x  = (const float*)d_in[0];
    const int*   ei = (const int*)d_in[1];
    const float* W1 = (const float*)d_in[2];
    const float* W2 = (const float*)d_in[3];
    const float* c1 = (const float*)d_in[4];
    const float* c2 = (const float*)d_in[5];
    float* out = (float*)d_out;

    const int N = in_sizes[0] / 512;  // 100000
    const int E = in_sizes[1] / 2;    // 800000

    // workspace carve-up (256B aligned)
    char* p = (char*)d_ws;
    size_t need = 0;
    auto alloc = [&](size_t bytes) {
        void* q = p;
        size_t pad = (bytes + 255) & ~(size_t)255;
        p += pad; need += pad;
        return q;
    };
    float* x1    = (float*)alloc((size_t)N * 256 * 4);
    float* x2    = (float*)alloc((size_t)N * 256 * 4);
    float* x3    = (float*)alloc((size_t)N * 256 * 4);
    int*   degs  = (int*)alloc((size_t)4 * N * 4);      // deg_in|deg_out|cur1|cur2
    int*   off1  = (int*)alloc((size_t)(N + 1) * 4);
    int*   off2  = (int*)alloc((size_t)(N + 1) * 4);
    int2*  ed1   = (int2*)alloc((size_t)E * 8);
    int2*  ed2   = (int2*)alloc((size_t)E * 8);
    unsigned short* W1th = (unsigned short*)alloc(512 * 256 * 2);
    unsigned short* W1tl = (unsigned short*)alloc(512 * 256 * 2);
    unsigned short* W2th = (unsigned short*)alloc(512 * 256 * 2);
    unsigned short* W2tl = (unsigned short*)alloc(512 * 256 * 2);
    int*   bs1   = (int*)alloc(1024 * 4);
    int*   bs2   = (int*)alloc(1024 * 4);
    if (need > ws_size) return;

    int* deg_in = degs, *deg_out = degs + N, *cur1 = degs + 2 * N, *cur2 = degs + 3 * N;

    hipMemsetAsync(degs, 0, (size_t)4 * N * 4, stream);

    const int eb = (E + 255) / 256;
    const int nb = (N + 255) / 256;
    split_w<<<(2 * 512 * 256) / 256, 256, 0, stream>>>(W1, W2, W1th, W1tl, W2th, W2tl);
    deg_kernel<<<eb, 256, 0, stream>>>(ei, E, deg_in, deg_out);
    block_sums2<<<nb, 256, 0, stream>>>(deg_in, deg_out, N, bs1, bs2);
    scan_small2<<<1, 512, 0, stream>>>(bs1, bs2, nb);
    scan_final2<<<nb, 256, 0, stream>>>(deg_in, deg_out, bs1, bs2, N, off1, off2);
    fill_kernel<<<eb, 256, 0, stream>>>(ei, E, deg_in, deg_out, off1, off2,
                                        cur1, cur2, ed1, ed2, c1, c2);

    dim3 gg((N + 127) / 128, 2);
    // x1 = x @ W1  (A chunks: x | x+256, lda 512)
    gemm_bf16x3<<<gg, 256, 0, stream>>>(x, x + 256, 512, W1th, W1tl, x1, N);
    // x2 = mish(mish(conv1(x1)))
    aggregate1<<<(N + 3) / 4, 256, 0, stream>>>(x1, off1, ed1, x2, N);
    // x3 = [x1|x2] @ W2  (A chunks: x1 | x2, lda 256)
    gemm_bf16x3<<<gg, 256, 0, stream>>>(x1, x2, 256, W2th, W2tl, x3, N);
    // x4 + final fuse -> out
    aggregate2<<<(N + 3) / 4, 256, 0, stream>>>(x3, off2, ed2, x1, x2, out, N);
}